// Round 7
// baseline (214.073 us; speedup 1.0000x reference)
//
#include <hip/hip_runtime.h>
#include <math.h>

#define NPOL   1000
#define NTICK  98000
#define NCOMM  1000
#define NN     100000
#define NE     1000000
#define NE2    1100000   // NE + NN self-loops

__device__ __forceinline__ unsigned short f2bf(float v) {
    unsigned u = __float_as_uint(v);
    u += 0x7FFFu + ((u >> 16) & 1u);          // round-to-nearest-even
    return (unsigned short)(u >> 16);
}
__device__ __forceinline__ float bf2f(unsigned short s) {
    return __uint_as_float(((unsigned)s) << 16);
}

// ---------------------------------------------------------------------------
// K1: node features -> LayerNorm -> h1 = x @ c1_W (bf16), scalars as1/ad1.
// All small weight tables staged in LDS: uniform-address ds_read is a
// broadcast (no s_load serialization — the R6 k_node failure mode).
__global__ void __launch_bounds__(256) k_node(
    const float* __restrict__ pol_feat, const int* __restrict__ state_ids,
    const int* __restrict__ sector_ids, const int* __restrict__ industry_ids,
    const float* __restrict__ comp_scalar,
    const float* __restrict__ pol_W, const float* __restrict__ pol_b,
    const float* __restrict__ state_E, const float* __restrict__ sector_E,
    const float* __restrict__ industry_E, const float* __restrict__ comp_W,
    const float* __restrict__ comp_b, const float* __restrict__ comm_E,
    const float* __restrict__ ln_g, const float* __restrict__ ln_b,
    const float* __restrict__ c1_W, const float* __restrict__ c1_as,
    const float* __restrict__ c1_ad,
    unsigned short* __restrict__ h1b, float* __restrict__ as1, float* __restrict__ ad1) {
    __shared__ float sW1[2048];     // c1_W  32x64
    __shared__ float sCompW[544];   // comp_W 17x32
    __shared__ float sPolW[224];    // pol_W 7x32
    __shared__ float sAs[64], sAd[64];
    __shared__ float sLg[32], sLb[32], sPb[32], sCb[32];
    int t = threadIdx.x;
    for (int i = t; i < 2048; i += 256) sW1[i] = c1_W[i];
    for (int i = t; i < 544; i += 256) sCompW[i] = comp_W[i];
    if (t < 224) sPolW[t] = pol_W[t];
    if (t < 64) { sAs[t] = c1_as[t]; sAd[t] = c1_ad[t]; }
    if (t < 32) { sLg[t] = ln_g[t]; sLb[t] = ln_b[t]; sPb[t] = pol_b[t]; sCb[t] = comp_b[t]; }
    __syncthreads();
    int n = blockIdx.x * blockDim.x + t;
    if (n >= NN) return;
    float x[32];
    if (n < NPOL) {
        float f[7];
        #pragma unroll
        for (int i = 0; i < 7; ++i) f[i] = pol_feat[n * 7 + i];
        int sid = state_ids[n];
        #pragma unroll
        for (int j = 0; j < 32; ++j) {
            float v = sPb[j];
            #pragma unroll
            for (int i = 0; i < 7; ++i) v += f[i] * sPolW[i * 32 + j];
            v = v > 0.f ? v : 0.f;
            x[j] = v + state_E[sid * 32 + j];
        }
    } else if (n < NPOL + NTICK) {
        int tt = n - NPOL;
        float f[17];
        int sec = sector_ids[tt], ind = industry_ids[tt];
        #pragma unroll
        for (int i = 0; i < 8; ++i) { f[i] = sector_E[sec * 8 + i]; f[8 + i] = industry_E[ind * 8 + i]; }
        f[16] = comp_scalar[tt];
        #pragma unroll
        for (int j = 0; j < 32; ++j) {
            float v = sCb[j];
            #pragma unroll
            for (int i = 0; i < 17; ++i) v += f[i] * sCompW[i * 32 + j];
            x[j] = v > 0.f ? v : 0.f;
        }
    } else {
        int c = n - (NPOL + NTICK);
        #pragma unroll
        for (int j = 0; j < 32; ++j) x[j] = comm_E[c * 32 + j];
    }
    float mu = 0.f;
    #pragma unroll
    for (int j = 0; j < 32; ++j) mu += x[j];
    mu *= (1.f / 32.f);
    float var = 0.f;
    #pragma unroll
    for (int j = 0; j < 32; ++j) { float d = x[j] - mu; var += d * d; }
    var *= (1.f / 32.f);
    float inv = rsqrtf(var + 1e-5f);
    #pragma unroll
    for (int j = 0; j < 32; ++j) x[j] = (x[j] - mu) * inv * sLg[j] + sLb[j];
    #pragma unroll
    for (int h = 0; h < 4; ++h) {
        float av = 0.f, dv = 0.f;
        for (int f = 0; f < 16; ++f) {
            int j = h * 16 + f;
            float v = 0.f;
            #pragma unroll
            for (int i = 0; i < 32; ++i) v += x[i] * sW1[i * 64 + j];
            h1b[n * 64 + j] = f2bf(v);
            av += v * sAs[j];
            dv += v * sAd[j];
        }
        as1[n * 4 + h] = av;
        ad1[n * 4 + h] = dv;
    }
}

// ---------------------------------------------------------------------------
// K2: in-degree count + per-edge rank (rank = order of arrival within dst).
__global__ void k_deg(const int* __restrict__ ei, int* __restrict__ deg,
                      int* __restrict__ ord) {
    int e = blockIdx.x * blockDim.x + threadIdx.x;
    if (e < NE) ord[e] = atomicAdd(&deg[ei[NE + e]], 1);
}

__global__ void k_scan1(const int* __restrict__ deg, int* __restrict__ row_start,
                        int* __restrict__ bsum) {
    __shared__ int tmp[1024];
    int i = blockIdx.x * 1024 + threadIdx.x;
    int v = (i < NN) ? deg[i] + 1 : 0;
    tmp[threadIdx.x] = v;
    __syncthreads();
    for (int off = 1; off < 1024; off <<= 1) {
        int t = (threadIdx.x >= off) ? tmp[threadIdx.x - off] : 0;
        __syncthreads();
        tmp[threadIdx.x] += t;
        __syncthreads();
    }
    if (i < NN) row_start[i] = tmp[threadIdx.x] - v;
    if (threadIdx.x == 1023) bsum[blockIdx.x] = tmp[1023];
}
__global__ void k_scan2(int* __restrict__ bsum, int nb) {
    __shared__ int tmp[128];
    int t = threadIdx.x;
    int v = (t < nb) ? bsum[t] : 0;
    tmp[t] = v;
    __syncthreads();
    for (int off = 1; off < 128; off <<= 1) {
        int u = (t >= off) ? tmp[t - off] : 0;
        __syncthreads();
        tmp[t] += u;
        __syncthreads();
    }
    if (t < nb) bsum[t] = tmp[t] - v;
}
__global__ void k_scan3(int* __restrict__ row_start, const int* __restrict__ bsum) {
    int i = blockIdx.x * blockDim.x + threadIdx.x;
    if (i < NN) row_start[i] += bsum[i >> 10];
}

// ---------------------------------------------------------------------------
// K4: CSR fill into packed 16B records {src i32, ae1 4xbf16, ae2 f32}. Slot
// row_start[d] reserved for the self-loop. Atomic-free via precomputed rank.
__global__ void __launch_bounds__(256) k_fill(
    const int* __restrict__ ei, const float* __restrict__ edge_attr,
    const int* __restrict__ row_start, const int* __restrict__ ord,
    const float* __restrict__ c1_eW, const float* __restrict__ c1_ae,
    const float* __restrict__ c2_eW, const float* __restrict__ c2_ae,
    float4* __restrict__ rec) {
    __shared__ float we1s[20];
    __shared__ float we2s[5];
    int t = threadIdx.x;
    if (t < 20) {
        int d = t >> 2, h = t & 3;
        float s = 0.f;
        for (int f = 0; f < 16; ++f) s += c1_eW[d * 64 + h * 16 + f] * c1_ae[h * 16 + f];
        we1s[t] = s;
    } else if (t >= 32 && t < 37) {
        int d = t - 32;
        float s = 0.f;
        for (int f = 0; f < 32; ++f) s += c2_eW[d * 32 + f] * c2_ae[f];
        we2s[d] = s;
    }
    __syncthreads();
    int e = blockIdx.x * blockDim.x + t;
    if (e >= NE) return;
    int s = ei[e], d = ei[NE + e];
    int pos = row_start[d] + 1 + ord[e];
    float a[5];
    #pragma unroll
    for (int k = 0; k < 5; ++k) a[k] = edge_attr[e * 5 + k];
    float e0 = 0.f, e1 = 0.f, e2 = 0.f, e3 = 0.f, e4 = 0.f;
    #pragma unroll
    for (int k = 0; k < 5; ++k) {
        e0 += a[k] * we1s[k * 4 + 0];
        e1 += a[k] * we1s[k * 4 + 1];
        e2 += a[k] * we1s[k * 4 + 2];
        e3 += a[k] * we1s[k * 4 + 3];
        e4 += a[k] * we2s[k];
    }
    unsigned u01 = (unsigned)f2bf(e0) | ((unsigned)f2bf(e1) << 16);
    unsigned u23 = (unsigned)f2bf(e2) | ((unsigned)f2bf(e3) << 16);
    rec[pos] = make_float4(__int_as_float(s), __uint_as_float(u01),
                           __uint_as_float(u23), e4);
}

// ---------------------------------------------------------------------------
// K6: GAT layer 1. One wave = 2 nodes (32 lanes each); lane owns dims {2j,2j+1}
// via one packed u32 h1b load. Two-phase per 32-edge chunk.
__global__ void __launch_bounds__(256) k_agg1(
    const int* __restrict__ row_start, const int* __restrict__ deg,
    float4* __restrict__ rec,
    const float* __restrict__ as1, const float* __restrict__ ad1,
    const unsigned short* __restrict__ h1b, const float* __restrict__ c1_b,
    unsigned short* __restrict__ x1b) {
    __shared__ float pT[4][2][32][4];
    __shared__ int   srcT[4][2][32];
    int wid = threadIdx.x >> 6;
    int lane = threadIdx.x & 63;
    int half = lane >> 5;
    int j = lane & 31;
    int h = j >> 3;
    int n = blockIdx.x * 8 + wid * 2 + half;
    int base = row_start[n];
    int dg   = deg[n];
    const float4* as1v4 = (const float4*)as1;
    const float4* ad1v4 = (const float4*)ad1;
    float4 adv = ad1v4[n];
    float4 asv = as1v4[n];
    unsigned uself = *(const unsigned*)(h1b + (unsigned)n * 64u + 2u * (unsigned)j);

    float ssum = 0.f, acc0 = 0.f, acc1 = 0.f;
    float aes0 = 0.f, aes1 = 0.f, aes2 = 0.f, aes3 = 0.f, ae2sum = 0.f;

    for (int i0 = 0; i0 < dg; i0 += 32) {
        int clen = dg - i0; if (clen > 32) clen = 32;
        int idx = i0 + j;
        if (idx < dg) {
            float4 r = rec[base + 1 + idx];
            int s = __float_as_int(r.x);
            unsigned u01 = __float_as_uint(r.y), u23 = __float_as_uint(r.z);
            float ae0  = bf2f((unsigned short)u01);
            float ae1v = bf2f((unsigned short)(u01 >> 16));
            float ae2v = bf2f((unsigned short)u23);
            float ae3v = bf2f((unsigned short)(u23 >> 16));
            float4 av = as1v4[s];
            float l0 = av.x + adv.x + ae0;  l0 = l0 > 0.f ? l0 : 0.2f * l0;
            float l1 = av.y + adv.y + ae1v; l1 = l1 > 0.f ? l1 : 0.2f * l1;
            float l2 = av.z + adv.z + ae2v; l2 = l2 > 0.f ? l2 : 0.2f * l2;
            float l3 = av.w + adv.w + ae3v; l3 = l3 > 0.f ? l3 : 0.2f * l3;
            float4 q = make_float4(__expf(l0), __expf(l1), __expf(l2), __expf(l3));
            *(float4*)&pT[wid][half][j][0] = q;
            srcT[wid][half][j] = s;
            aes0 += ae0; aes1 += ae1v; aes2 += ae2v; aes3 += ae3v;
            ae2sum += r.w;
        }
        int i = 0;
        for (; i + 4 <= clen; i += 4) {
            int s0 = srcT[wid][half][i],     s1 = srcT[wid][half][i + 1];
            int s2 = srcT[wid][half][i + 2], s3 = srcT[wid][half][i + 3];
            float q0 = pT[wid][half][i][h],     q1 = pT[wid][half][i + 1][h];
            float q2 = pT[wid][half][i + 2][h], q3 = pT[wid][half][i + 3][h];
            unsigned g0 = *(const unsigned*)(h1b + (unsigned)s0 * 64u + 2u * (unsigned)j);
            unsigned g1 = *(const unsigned*)(h1b + (unsigned)s1 * 64u + 2u * (unsigned)j);
            unsigned g2 = *(const unsigned*)(h1b + (unsigned)s2 * 64u + 2u * (unsigned)j);
            unsigned g3 = *(const unsigned*)(h1b + (unsigned)s3 * 64u + 2u * (unsigned)j);
            ssum += (q0 + q1) + (q2 + q3);
            acc0 = fmaf(q0, bf2f((unsigned short)g0),
                   fmaf(q1, bf2f((unsigned short)g1),
                   fmaf(q2, bf2f((unsigned short)g2),
                   fmaf(q3, bf2f((unsigned short)g3), acc0))));
            acc1 = fmaf(q0, bf2f((unsigned short)(g0 >> 16)),
                   fmaf(q1, bf2f((unsigned short)(g1 >> 16)),
                   fmaf(q2, bf2f((unsigned short)(g2 >> 16)),
                   fmaf(q3, bf2f((unsigned short)(g3 >> 16)), acc1))));
        }
        for (; i < clen; ++i) {
            int s0 = srcT[wid][half][i];
            float q0 = pT[wid][half][i][h];
            unsigned g0 = *(const unsigned*)(h1b + (unsigned)s0 * 64u + 2u * (unsigned)j);
            ssum += q0;
            acc0 = fmaf(q0, bf2f((unsigned short)g0), acc0);
            acc1 = fmaf(q0, bf2f((unsigned short)(g0 >> 16)), acc1);
        }
    }
    #pragma unroll
    for (int m = 1; m < 32; m <<= 1) {
        aes0 += __shfl_xor(aes0, m);
        aes1 += __shfl_xor(aes1, m);
        aes2 += __shfl_xor(aes2, m);
        aes3 += __shfl_xor(aes3, m);
        ae2sum += __shfl_xor(ae2sum, m);
    }
    float invd = 1.f / fmaxf((float)dg, 1.f);
    float aesh = (h == 0) ? aes0 : (h == 1) ? aes1 : (h == 2) ? aes2 : aes3;
    float adh  = (h == 0) ? adv.x : (h == 1) ? adv.y : (h == 2) ? adv.z : adv.w;
    float ash  = (h == 0) ? asv.x : (h == 1) ? asv.y : (h == 2) ? asv.z : asv.w;
    float ls = ash + adh + aesh * invd;
    ls = ls > 0.f ? ls : 0.2f * ls;
    float ps = __expf(ls);
    ssum += ps;
    acc0 = fmaf(ps, bf2f((unsigned short)uself), acc0);
    acc1 = fmaf(ps, bf2f((unsigned short)(uself >> 16)), acc1);
    if (j == 0) {
        rec[base] = make_float4(__int_as_float(n), 0.f, 0.f, ae2sum * invd);
    }
    float inv_s = 1.f / ssum;
    float x0 = acc0 * inv_s + c1_b[2 * j];
    float x1 = acc1 * inv_s + c1_b[2 * j + 1];
    x0 = (x0 > 0.f) ? x0 : (__expf(x0) - 1.f);   // ELU
    x1 = (x1 > 0.f) ? x1 : (__expf(x1) - 1.f);
    unsigned w = (unsigned)f2bf(x0) | ((unsigned)f2bf(x1) << 16);
    *(unsigned*)(x1b + (unsigned)n * 64u + 2u * (unsigned)j) = w;
}

// ---------------------------------------------------------------------------
// K6.5: wave-cooperative GEMV h2 = x1 @ c2_W (64->32) + as2/ad2 scalars.
__global__ void __launch_bounds__(256) k_mid(
    const unsigned short* __restrict__ x1b, const float* __restrict__ c2_W,
    const float* __restrict__ c2_as, const float* __restrict__ c2_ad,
    unsigned short* __restrict__ h2b, float* __restrict__ as2,
    float* __restrict__ ad2) {
    int wave = (blockIdx.x * 256 + threadIdx.x) >> 6;   // 50000 waves exactly
    int lane = threadIdx.x & 63;
    int half = lane >> 5, j = lane & 31;
    int n = wave * 2 + half;
    unsigned u = *(const unsigned*)(x1b + (unsigned)n * 64u + j * 2u);
    float acc = 0.f;
    #pragma unroll
    for (int t = 0; t < 32; ++t) {
        unsigned xu = (unsigned)__shfl((int)u, half * 32 + t, 64);
        float x0 = bf2f((unsigned short)xu);
        float x1 = bf2f((unsigned short)(xu >> 16));
        acc = fmaf(x0, c2_W[(2 * t) * 32 + j], acc);
        acc = fmaf(x1, c2_W[(2 * t + 1) * 32 + j], acc);
    }
    float a = acc * c2_as[j], b = acc * c2_ad[j];
    #pragma unroll
    for (int m = 16; m > 0; m >>= 1) {
        a += __shfl_xor(a, m, 64);
        b += __shfl_xor(b, m, 64);
    }
    if (j == 0) { as2[n] = a; ad2[n] = b; }
    h2b[(unsigned)n * 32u + j] = f2bf(acc);
}

// ---------------------------------------------------------------------------
// K7: GAT layer 2, one 32-lane group per dst, two-phase, writes d_out.
__global__ void __launch_bounds__(256) k_agg2(
    const int* __restrict__ row_start, const int* __restrict__ deg,
    const float4* __restrict__ rec, const float* __restrict__ as2,
    const float* __restrict__ ad2, const unsigned short* __restrict__ h2b,
    const float* __restrict__ c2_b, float* __restrict__ out) {
    __shared__ float2 spT[8][32];
    int t = threadIdx.x;
    int half = t >> 5;
    int l32 = t & 31;
    int n = blockIdx.x * 8 + half;
    int base = row_start[n];
    int len = deg[n] + 1;
    float ad2n = ad2[n];
    float ssum = 0.f, acc = 0.f;
    for (int i0 = 0; i0 < len; i0 += 32) {
        int clen = len - i0; if (clen > 32) clen = 32;
        int idx = i0 + l32;
        float p = 0.f; int s = 0;
        if (idx < len) {
            float4 r = rec[base + idx];
            s = __float_as_int(r.x);
            float l = as2[s] + ad2n + r.w;
            l = l > 0.f ? l : 0.2f * l;
            p = __expf(l);
        }
        ssum += p;
        spT[half][l32] = make_float2(__int_as_float(s), p);
        int i = 0;
        for (; i + 4 <= clen; i += 4) {
            float2 e0 = spT[half][i],     e1 = spT[half][i + 1];
            float2 e2 = spT[half][i + 2], e3 = spT[half][i + 3];
            int s0 = __float_as_int(e0.x), s1 = __float_as_int(e1.x);
            int s2 = __float_as_int(e2.x), s3 = __float_as_int(e3.x);
            float g0 = bf2f(h2b[(unsigned)s0 * 32u + l32]);
            float g1 = bf2f(h2b[(unsigned)s1 * 32u + l32]);
            float g2 = bf2f(h2b[(unsigned)s2 * 32u + l32]);
            float g3 = bf2f(h2b[(unsigned)s3 * 32u + l32]);
            acc = fmaf(e0.y, g0, fmaf(e1.y, g1, fmaf(e2.y, g2, fmaf(e3.y, g3, acc))));
        }
        for (; i < clen; ++i) {
            float2 e0 = spT[half][i];
            int s0 = __float_as_int(e0.x);
            acc = fmaf(e0.y, bf2f(h2b[(unsigned)s0 * 32u + l32]), acc);
        }
    }
    #pragma unroll
    for (int m = 1; m < 32; m <<= 1) ssum += __shfl_xor(ssum, m, 32);
    out[(size_t)n * 32 + l32] = acc / ssum + c2_b[l32];
}

// ---------------------------------------------------------------------------
extern "C" void kernel_launch(void* const* d_in, const int* in_sizes, int n_in,
                              void* d_out, int out_size, void* d_ws, size_t ws_size,
                              hipStream_t stream) {
    const int*   edge_index  = (const int*)  d_in[0];
    const float* edge_attr   = (const float*)d_in[1];
    const float* pol_feat    = (const float*)d_in[2];
    const int*   state_ids   = (const int*)  d_in[3];
    const int*   sector_ids  = (const int*)  d_in[4];
    const int*   industry_ids= (const int*)  d_in[5];
    const float* comp_scalar = (const float*)d_in[6];
    const float* pol_W   = (const float*)d_in[7];
    const float* pol_b   = (const float*)d_in[8];
    const float* state_E = (const float*)d_in[9];
    const float* sector_E= (const float*)d_in[10];
    const float* industry_E=(const float*)d_in[11];
    const float* comp_W  = (const float*)d_in[12];
    const float* comp_b  = (const float*)d_in[13];
    const float* comm_E  = (const float*)d_in[14];
    const float* ln_g    = (const float*)d_in[15];
    const float* ln_b    = (const float*)d_in[16];
    const float* c1_W    = (const float*)d_in[17];
    const float* c1_as   = (const float*)d_in[18];
    const float* c1_ad   = (const float*)d_in[19];
    const float* c1_eW   = (const float*)d_in[20];
    const float* c1_ae   = (const float*)d_in[21];
    const float* c1_b    = (const float*)d_in[22];
    const float* c2_W    = (const float*)d_in[23];
    const float* c2_as   = (const float*)d_in[24];
    const float* c2_ad   = (const float*)d_in[25];
    const float* c2_eW   = (const float*)d_in[26];
    const float* c2_ae   = (const float*)d_in[27];
    const float* c2_b    = (const float*)d_in[28];
    float* out = (float*)d_out;

    char* ws = (char*)d_ws;
    size_t off = 0;
    auto alloc = [&](size_t bytes) { void* p = ws + off; off += (bytes + 255) & ~(size_t)255; return p; };
    int*   deg       = (int*)  alloc(NN * 4);
    int*   ord       = (int*)  alloc((size_t)NE * 4);
    int*   row_start = (int*)  alloc(NN * 4);
    int*   bsum      = (int*)  alloc(128 * 4);
    float4* rec      = (float4*)alloc((size_t)NE2 * 16);
    unsigned short* h1b = (unsigned short*)alloc((size_t)NN * 64 * 2);
    float* as1       = (float*)alloc((size_t)NN * 4 * 4);
    float* ad1       = (float*)alloc((size_t)NN * 4 * 4);
    unsigned short* x1b = (unsigned short*)alloc((size_t)NN * 64 * 2);
    unsigned short* h2b = (unsigned short*)alloc((size_t)NN * 32 * 2);
    float* as2       = (float*)alloc(NN * 4);
    float* ad2       = (float*)alloc(NN * 4);
    (void)ws_size; (void)in_sizes; (void)n_in; (void)out_size;

    hipMemsetAsync(deg, 0, NN * 4, stream);

    k_node<<<(NN + 255) / 256, 256, 0, stream>>>(
        pol_feat, state_ids, sector_ids, industry_ids, comp_scalar,
        pol_W, pol_b, state_E, sector_E, industry_E, comp_W, comp_b, comm_E,
        ln_g, ln_b, c1_W, c1_as, c1_ad, h1b, as1, ad1);
    k_deg<<<(NE + 255) / 256, 256, 0, stream>>>(edge_index, deg, ord);
    int nblk = (NN + 1023) / 1024;   // 98
    k_scan1<<<nblk, 1024, 0, stream>>>(deg, row_start, bsum);
    k_scan2<<<1, 128, 0, stream>>>(bsum, nblk);
    k_scan3<<<(NN + 255) / 256, 256, 0, stream>>>(row_start, bsum);
    k_fill<<<(NE + 255) / 256, 256, 0, stream>>>(
        edge_index, edge_attr, row_start, ord, c1_eW, c1_ae, c2_eW, c2_ae, rec);
    k_agg1<<<NN / 8, 256, 0, stream>>>(
        row_start, deg, rec, as1, ad1, h1b, c1_b, x1b);
    k_mid<<<(NN / 2) / 4, 256, 0, stream>>>(          // 50000 waves = 12500 blocks
        x1b, c2_W, c2_as, c2_ad, h2b, as2, ad2);
    k_agg2<<<NN / 8, 256, 0, stream>>>(
        row_start, deg, rec, as2, ad2, h2b, c2_b, out);
}

// Round 8
// 200.310 us; speedup vs baseline: 1.0687x; 1.0687x over previous
//
#include <hip/hip_runtime.h>
#include <math.h>

#define NPOL   1000
#define NTICK  98000
#define NCOMM  1000
#define NN     100000
#define NE     1000000
#define NE2    1100000   // NE + NN self-loops

__device__ __forceinline__ unsigned short f2bf(float v) {
    unsigned u = __float_as_uint(v);
    u += 0x7FFFu + ((u >> 16) & 1u);          // round-to-nearest-even
    return (unsigned short)(u >> 16);
}
__device__ __forceinline__ float bf2f(unsigned short s) {
    return __uint_as_float(((unsigned)s) << 16);
}

// ---------------------------------------------------------------------------
// K1: node features -> LayerNorm -> h1 = x @ c1_W (bf16), scalars as1/ad1.
// 4 threads per node (q = head): shared x recomputed per thread, each thread
// does 16 of 64 h1 columns. Grid 400k threads -> ~24 waves/CU (the R7 version
// was 391 blocks = 1 wave/SIMD, pure latency-bound at 12% occupancy).
__global__ void __launch_bounds__(256) k_node(
    const float* __restrict__ pol_feat, const int* __restrict__ state_ids,
    const int* __restrict__ sector_ids, const int* __restrict__ industry_ids,
    const float* __restrict__ comp_scalar,
    const float* __restrict__ pol_W, const float* __restrict__ pol_b,
    const float* __restrict__ state_E, const float* __restrict__ sector_E,
    const float* __restrict__ industry_E, const float* __restrict__ comp_W,
    const float* __restrict__ comp_b, const float* __restrict__ comm_E,
    const float* __restrict__ ln_g, const float* __restrict__ ln_b,
    const float* __restrict__ c1_W, const float* __restrict__ c1_as,
    const float* __restrict__ c1_ad,
    unsigned short* __restrict__ h1b, float* __restrict__ as1, float* __restrict__ ad1) {
    __shared__ float sW1[2048];     // c1_W  32x64
    __shared__ float sCompW[544];   // comp_W 17x32
    __shared__ float sPolW[224];    // pol_W 7x32
    __shared__ float sAs[64], sAd[64];
    __shared__ float sLg[32], sLb[32], sPb[32], sCb[32];
    int t = threadIdx.x;
    for (int i = t; i < 2048; i += 256) sW1[i] = c1_W[i];
    for (int i = t; i < 544; i += 256) sCompW[i] = comp_W[i];
    if (t < 224) sPolW[t] = pol_W[t];
    if (t < 64) { sAs[t] = c1_as[t]; sAd[t] = c1_ad[t]; }
    if (t < 32) { sLg[t] = ln_g[t]; sLb[t] = ln_b[t]; sPb[t] = pol_b[t]; sCb[t] = comp_b[t]; }
    __syncthreads();
    int tid = blockIdx.x * 256 + t;
    int n = tid >> 2;
    int q = tid & 3;
    if (n >= NN) return;
    float x[32];
    if (n < NPOL) {
        float f[7];
        #pragma unroll
        for (int i = 0; i < 7; ++i) f[i] = pol_feat[n * 7 + i];
        int sid = state_ids[n];
        #pragma unroll
        for (int j = 0; j < 32; ++j) {
            float v = sPb[j];
            #pragma unroll
            for (int i = 0; i < 7; ++i) v += f[i] * sPolW[i * 32 + j];
            v = v > 0.f ? v : 0.f;
            x[j] = v + state_E[sid * 32 + j];
        }
    } else if (n < NPOL + NTICK) {
        int tt = n - NPOL;
        float f[17];
        int sec = sector_ids[tt], ind = industry_ids[tt];
        #pragma unroll
        for (int i = 0; i < 8; ++i) { f[i] = sector_E[sec * 8 + i]; f[8 + i] = industry_E[ind * 8 + i]; }
        f[16] = comp_scalar[tt];
        #pragma unroll
        for (int j = 0; j < 32; ++j) {
            float v = sCb[j];
            #pragma unroll
            for (int i = 0; i < 17; ++i) v += f[i] * sCompW[i * 32 + j];
            x[j] = v > 0.f ? v : 0.f;
        }
    } else {
        int c = n - (NPOL + NTICK);
        #pragma unroll
        for (int j = 0; j < 32; ++j) x[j] = comm_E[c * 32 + j];
    }
    float mu = 0.f;
    #pragma unroll
    for (int j = 0; j < 32; ++j) mu += x[j];
    mu *= (1.f / 32.f);
    float var = 0.f;
    #pragma unroll
    for (int j = 0; j < 32; ++j) { float d = x[j] - mu; var += d * d; }
    var *= (1.f / 32.f);
    float inv = rsqrtf(var + 1e-5f);
    #pragma unroll
    for (int j = 0; j < 32; ++j) x[j] = (x[j] - mu) * inv * sLg[j] + sLb[j];
    // this thread's 16 columns (head q)
    float av = 0.f, dv = 0.f;
    unsigned pk[8];
    #pragma unroll
    for (int f2 = 0; f2 < 8; ++f2) {
        int j0 = q * 16 + 2 * f2;
        float v0 = 0.f, v1 = 0.f;
        #pragma unroll
        for (int i = 0; i < 32; ++i) {
            v0 += x[i] * sW1[i * 64 + j0];
            v1 += x[i] * sW1[i * 64 + j0 + 1];
        }
        av += v0 * sAs[j0] + v1 * sAs[j0 + 1];
        dv += v0 * sAd[j0] + v1 * sAd[j0 + 1];
        pk[f2] = (unsigned)f2bf(v0) | ((unsigned)f2bf(v1) << 16);
    }
    unsigned short* hp = h1b + (unsigned)n * 64u + (unsigned)q * 16u;
    *(uint4*)hp       = make_uint4(pk[0], pk[1], pk[2], pk[3]);
    *(uint4*)(hp + 8) = make_uint4(pk[4], pk[5], pk[6], pk[7]);
    as1[tid] = av;   // as1[n*4+q]
    ad1[tid] = dv;
}

// ---------------------------------------------------------------------------
// K2: in-degree count + per-edge rank (rank = order of arrival within dst).
__global__ void k_deg(const int* __restrict__ ei, int* __restrict__ deg,
                      int* __restrict__ ord) {
    int e = blockIdx.x * blockDim.x + threadIdx.x;
    if (e < NE) ord[e] = atomicAdd(&deg[ei[NE + e]], 1);
}

__global__ void k_scan1(const int* __restrict__ deg, int* __restrict__ row_start,
                        int* __restrict__ bsum) {
    __shared__ int tmp[1024];
    int i = blockIdx.x * 1024 + threadIdx.x;
    int v = (i < NN) ? deg[i] + 1 : 0;
    tmp[threadIdx.x] = v;
    __syncthreads();
    for (int off = 1; off < 1024; off <<= 1) {
        int t = (threadIdx.x >= off) ? tmp[threadIdx.x - off] : 0;
        __syncthreads();
        tmp[threadIdx.x] += t;
        __syncthreads();
    }
    if (i < NN) row_start[i] = tmp[threadIdx.x] - v;
    if (threadIdx.x == 1023) bsum[blockIdx.x] = tmp[1023];
}
__global__ void k_scan2(int* __restrict__ bsum, int nb) {
    __shared__ int tmp[128];
    int t = threadIdx.x;
    int v = (t < nb) ? bsum[t] : 0;
    tmp[t] = v;
    __syncthreads();
    for (int off = 1; off < 128; off <<= 1) {
        int u = (t >= off) ? tmp[t - off] : 0;
        __syncthreads();
        tmp[t] += u;
        __syncthreads();
    }
    if (t < nb) bsum[t] = tmp[t] - v;
}
__global__ void k_scan3(int* __restrict__ row_start, const int* __restrict__ bsum) {
    int i = blockIdx.x * blockDim.x + threadIdx.x;
    if (i < NN) row_start[i] += bsum[i >> 10];
}

// ---------------------------------------------------------------------------
// K4: CSR fill into packed 16B records {src i32, ae1 4xbf16, ae2 f32}. Slot
// row_start[d] reserved for the self-loop. Atomic-free via precomputed rank.
__global__ void __launch_bounds__(256) k_fill(
    const int* __restrict__ ei, const float* __restrict__ edge_attr,
    const int* __restrict__ row_start, const int* __restrict__ ord,
    const float* __restrict__ c1_eW, const float* __restrict__ c1_ae,
    const float* __restrict__ c2_eW, const float* __restrict__ c2_ae,
    float4* __restrict__ rec) {
    __shared__ float we1s[20];
    __shared__ float we2s[5];
    int t = threadIdx.x;
    if (t < 20) {
        int d = t >> 2, h = t & 3;
        float s = 0.f;
        for (int f = 0; f < 16; ++f) s += c1_eW[d * 64 + h * 16 + f] * c1_ae[h * 16 + f];
        we1s[t] = s;
    } else if (t >= 32 && t < 37) {
        int d = t - 32;
        float s = 0.f;
        for (int f = 0; f < 32; ++f) s += c2_eW[d * 32 + f] * c2_ae[f];
        we2s[d] = s;
    }
    __syncthreads();
    int e = blockIdx.x * blockDim.x + t;
    if (e >= NE) return;
    int s = ei[e], d = ei[NE + e];
    int pos = row_start[d] + 1 + ord[e];
    float a[5];
    #pragma unroll
    for (int k = 0; k < 5; ++k) a[k] = edge_attr[e * 5 + k];
    float e0 = 0.f, e1 = 0.f, e2 = 0.f, e3 = 0.f, e4 = 0.f;
    #pragma unroll
    for (int k = 0; k < 5; ++k) {
        e0 += a[k] * we1s[k * 4 + 0];
        e1 += a[k] * we1s[k * 4 + 1];
        e2 += a[k] * we1s[k * 4 + 2];
        e3 += a[k] * we1s[k * 4 + 3];
        e4 += a[k] * we2s[k];
    }
    unsigned u01 = (unsigned)f2bf(e0) | ((unsigned)f2bf(e1) << 16);
    unsigned u23 = (unsigned)f2bf(e2) | ((unsigned)f2bf(e3) << 16);
    rec[pos] = make_float4(__int_as_float(s), __uint_as_float(u01),
                           __uint_as_float(u23), e4);
}

// ---------------------------------------------------------------------------
// K6: GAT layer 1. One wave = 2 nodes (32 lanes each); lane owns dims {2j,2j+1}
// via one packed u32 h1b load. Two-phase per 32-edge chunk.
__global__ void __launch_bounds__(256) k_agg1(
    const int* __restrict__ row_start, const int* __restrict__ deg,
    float4* __restrict__ rec,
    const float* __restrict__ as1, const float* __restrict__ ad1,
    const unsigned short* __restrict__ h1b, const float* __restrict__ c1_b,
    unsigned short* __restrict__ x1b) {
    __shared__ float pT[4][2][32][4];
    __shared__ int   srcT[4][2][32];
    int wid = threadIdx.x >> 6;
    int lane = threadIdx.x & 63;
    int half = lane >> 5;
    int j = lane & 31;
    int h = j >> 3;
    int n = blockIdx.x * 8 + wid * 2 + half;
    int base = row_start[n];
    int dg   = deg[n];
    const float4* as1v4 = (const float4*)as1;
    const float4* ad1v4 = (const float4*)ad1;
    float4 adv = ad1v4[n];
    float4 asv = as1v4[n];
    unsigned uself = *(const unsigned*)(h1b + (unsigned)n * 64u + 2u * (unsigned)j);

    float ssum = 0.f, acc0 = 0.f, acc1 = 0.f;
    float aes0 = 0.f, aes1 = 0.f, aes2 = 0.f, aes3 = 0.f, ae2sum = 0.f;

    for (int i0 = 0; i0 < dg; i0 += 32) {
        int clen = dg - i0; if (clen > 32) clen = 32;
        int idx = i0 + j;
        if (idx < dg) {
            float4 r = rec[base + 1 + idx];
            int s = __float_as_int(r.x);
            unsigned u01 = __float_as_uint(r.y), u23 = __float_as_uint(r.z);
            float ae0  = bf2f((unsigned short)u01);
            float ae1v = bf2f((unsigned short)(u01 >> 16));
            float ae2v = bf2f((unsigned short)u23);
            float ae3v = bf2f((unsigned short)(u23 >> 16));
            float4 av = as1v4[s];
            float l0 = av.x + adv.x + ae0;  l0 = l0 > 0.f ? l0 : 0.2f * l0;
            float l1 = av.y + adv.y + ae1v; l1 = l1 > 0.f ? l1 : 0.2f * l1;
            float l2 = av.z + adv.z + ae2v; l2 = l2 > 0.f ? l2 : 0.2f * l2;
            float l3 = av.w + adv.w + ae3v; l3 = l3 > 0.f ? l3 : 0.2f * l3;
            float4 q = make_float4(__expf(l0), __expf(l1), __expf(l2), __expf(l3));
            *(float4*)&pT[wid][half][j][0] = q;
            srcT[wid][half][j] = s;
            aes0 += ae0; aes1 += ae1v; aes2 += ae2v; aes3 += ae3v;
            ae2sum += r.w;
        }
        int i = 0;
        for (; i + 4 <= clen; i += 4) {
            int s0 = srcT[wid][half][i],     s1 = srcT[wid][half][i + 1];
            int s2 = srcT[wid][half][i + 2], s3 = srcT[wid][half][i + 3];
            float q0 = pT[wid][half][i][h],     q1 = pT[wid][half][i + 1][h];
            float q2 = pT[wid][half][i + 2][h], q3 = pT[wid][half][i + 3][h];
            unsigned g0 = *(const unsigned*)(h1b + (unsigned)s0 * 64u + 2u * (unsigned)j);
            unsigned g1 = *(const unsigned*)(h1b + (unsigned)s1 * 64u + 2u * (unsigned)j);
            unsigned g2 = *(const unsigned*)(h1b + (unsigned)s2 * 64u + 2u * (unsigned)j);
            unsigned g3 = *(const unsigned*)(h1b + (unsigned)s3 * 64u + 2u * (unsigned)j);
            ssum += (q0 + q1) + (q2 + q3);
            acc0 = fmaf(q0, bf2f((unsigned short)g0),
                   fmaf(q1, bf2f((unsigned short)g1),
                   fmaf(q2, bf2f((unsigned short)g2),
                   fmaf(q3, bf2f((unsigned short)g3), acc0))));
            acc1 = fmaf(q0, bf2f((unsigned short)(g0 >> 16)),
                   fmaf(q1, bf2f((unsigned short)(g1 >> 16)),
                   fmaf(q2, bf2f((unsigned short)(g2 >> 16)),
                   fmaf(q3, bf2f((unsigned short)(g3 >> 16)), acc1))));
        }
        for (; i < clen; ++i) {
            int s0 = srcT[wid][half][i];
            float q0 = pT[wid][half][i][h];
            unsigned g0 = *(const unsigned*)(h1b + (unsigned)s0 * 64u + 2u * (unsigned)j);
            ssum += q0;
            acc0 = fmaf(q0, bf2f((unsigned short)g0), acc0);
            acc1 = fmaf(q0, bf2f((unsigned short)(g0 >> 16)), acc1);
        }
    }
    #pragma unroll
    for (int m = 1; m < 32; m <<= 1) {
        aes0 += __shfl_xor(aes0, m);
        aes1 += __shfl_xor(aes1, m);
        aes2 += __shfl_xor(aes2, m);
        aes3 += __shfl_xor(aes3, m);
        ae2sum += __shfl_xor(ae2sum, m);
    }
    float invd = 1.f / fmaxf((float)dg, 1.f);
    float aesh = (h == 0) ? aes0 : (h == 1) ? aes1 : (h == 2) ? aes2 : aes3;
    float adh  = (h == 0) ? adv.x : (h == 1) ? adv.y : (h == 2) ? adv.z : adv.w;
    float ash  = (h == 0) ? asv.x : (h == 1) ? asv.y : (h == 2) ? asv.z : asv.w;
    float ls = ash + adh + aesh * invd;
    ls = ls > 0.f ? ls : 0.2f * ls;
    float ps = __expf(ls);
    ssum += ps;
    acc0 = fmaf(ps, bf2f((unsigned short)uself), acc0);
    acc1 = fmaf(ps, bf2f((unsigned short)(uself >> 16)), acc1);
    if (j == 0) {
        rec[base] = make_float4(__int_as_float(n), 0.f, 0.f, ae2sum * invd);
    }
    float inv_s = 1.f / ssum;
    float x0 = acc0 * inv_s + c1_b[2 * j];
    float x1 = acc1 * inv_s + c1_b[2 * j + 1];
    x0 = (x0 > 0.f) ? x0 : (__expf(x0) - 1.f);   // ELU
    x1 = (x1 > 0.f) ? x1 : (__expf(x1) - 1.f);
    unsigned w = (unsigned)f2bf(x0) | ((unsigned)f2bf(x1) << 16);
    *(unsigned*)(x1b + (unsigned)n * 64u + 2u * (unsigned)j) = w;
}

// ---------------------------------------------------------------------------
// K6.5: wave-cooperative GEMV h2 = x1 @ c2_W (64->32) + as2/ad2 scalars.
__global__ void __launch_bounds__(256) k_mid(
    const unsigned short* __restrict__ x1b, const float* __restrict__ c2_W,
    const float* __restrict__ c2_as, const float* __restrict__ c2_ad,
    unsigned short* __restrict__ h2b, float* __restrict__ as2,
    float* __restrict__ ad2) {
    int wave = (blockIdx.x * 256 + threadIdx.x) >> 6;   // 50000 waves exactly
    int lane = threadIdx.x & 63;
    int half = lane >> 5, j = lane & 31;
    int n = wave * 2 + half;
    unsigned u = *(const unsigned*)(x1b + (unsigned)n * 64u + j * 2u);
    float acc = 0.f;
    #pragma unroll
    for (int t = 0; t < 32; ++t) {
        unsigned xu = (unsigned)__shfl((int)u, half * 32 + t, 64);
        float x0 = bf2f((unsigned short)xu);
        float x1 = bf2f((unsigned short)(xu >> 16));
        acc = fmaf(x0, c2_W[(2 * t) * 32 + j], acc);
        acc = fmaf(x1, c2_W[(2 * t + 1) * 32 + j], acc);
    }
    float a = acc * c2_as[j], b = acc * c2_ad[j];
    #pragma unroll
    for (int m = 16; m > 0; m >>= 1) {
        a += __shfl_xor(a, m, 64);
        b += __shfl_xor(b, m, 64);
    }
    if (j == 0) { as2[n] = a; ad2[n] = b; }
    h2b[(unsigned)n * 32u + j] = f2bf(acc);
}

// ---------------------------------------------------------------------------
// K7: GAT layer 2, one 32-lane group per dst, two-phase, writes d_out.
__global__ void __launch_bounds__(256) k_agg2(
    const int* __restrict__ row_start, const int* __restrict__ deg,
    const float4* __restrict__ rec, const float* __restrict__ as2,
    const float* __restrict__ ad2, const unsigned short* __restrict__ h2b,
    const float* __restrict__ c2_b, float* __restrict__ out) {
    __shared__ float2 spT[8][32];
    int t = threadIdx.x;
    int half = t >> 5;
    int l32 = t & 31;
    int n = blockIdx.x * 8 + half;
    int base = row_start[n];
    int len = deg[n] + 1;
    float ad2n = ad2[n];
    float ssum = 0.f, acc = 0.f;
    for (int i0 = 0; i0 < len; i0 += 32) {
        int clen = len - i0; if (clen > 32) clen = 32;
        int idx = i0 + l32;
        float p = 0.f; int s = 0;
        if (idx < len) {
            float4 r = rec[base + idx];
            s = __float_as_int(r.x);
            float l = as2[s] + ad2n + r.w;
            l = l > 0.f ? l : 0.2f * l;
            p = __expf(l);
        }
        ssum += p;
        spT[half][l32] = make_float2(__int_as_float(s), p);
        int i = 0;
        for (; i + 4 <= clen; i += 4) {
            float2 e0 = spT[half][i],     e1 = spT[half][i + 1];
            float2 e2 = spT[half][i + 2], e3 = spT[half][i + 3];
            int s0 = __float_as_int(e0.x), s1 = __float_as_int(e1.x);
            int s2 = __float_as_int(e2.x), s3 = __float_as_int(e3.x);
            float g0 = bf2f(h2b[(unsigned)s0 * 32u + l32]);
            float g1 = bf2f(h2b[(unsigned)s1 * 32u + l32]);
            float g2 = bf2f(h2b[(unsigned)s2 * 32u + l32]);
            float g3 = bf2f(h2b[(unsigned)s3 * 32u + l32]);
            acc = fmaf(e0.y, g0, fmaf(e1.y, g1, fmaf(e2.y, g2, fmaf(e3.y, g3, acc))));
        }
        for (; i < clen; ++i) {
            float2 e0 = spT[half][i];
            int s0 = __float_as_int(e0.x);
            acc = fmaf(e0.y, bf2f(h2b[(unsigned)s0 * 32u + l32]), acc);
        }
    }
    #pragma unroll
    for (int m = 1; m < 32; m <<= 1) ssum += __shfl_xor(ssum, m, 32);
    out[(size_t)n * 32 + l32] = acc / ssum + c2_b[l32];
}

// ---------------------------------------------------------------------------
extern "C" void kernel_launch(void* const* d_in, const int* in_sizes, int n_in,
                              void* d_out, int out_size, void* d_ws, size_t ws_size,
                              hipStream_t stream) {
    const int*   edge_index  = (const int*)  d_in[0];
    const float* edge_attr   = (const float*)d_in[1];
    const float* pol_feat    = (const float*)d_in[2];
    const int*   state_ids   = (const int*)  d_in[3];
    const int*   sector_ids  = (const int*)  d_in[4];
    const int*   industry_ids= (const int*)  d_in[5];
    const float* comp_scalar = (const float*)d_in[6];
    const float* pol_W   = (const float*)d_in[7];
    const float* pol_b   = (const float*)d_in[8];
    const float* state_E = (const float*)d_in[9];
    const float* sector_E= (const float*)d_in[10];
    const float* industry_E=(const float*)d_in[11];
    const float* comp_W  = (const float*)d_in[12];
    const float* comp_b  = (const float*)d_in[13];
    const float* comm_E  = (const float*)d_in[14];
    const float* ln_g    = (const float*)d_in[15];
    const float* ln_b    = (const float*)d_in[16];
    const float* c1_W    = (const float*)d_in[17];
    const float* c1_as   = (const float*)d_in[18];
    const float* c1_ad   = (const float*)d_in[19];
    const float* c1_eW   = (const float*)d_in[20];
    const float* c1_ae   = (const float*)d_in[21];
    const float* c1_b    = (const float*)d_in[22];
    const float* c2_W    = (const float*)d_in[23];
    const float* c2_as   = (const float*)d_in[24];
    const float* c2_ad   = (const float*)d_in[25];
    const float* c2_eW   = (const float*)d_in[26];
    const float* c2_ae   = (const float*)d_in[27];
    const float* c2_b    = (const float*)d_in[28];
    float* out = (float*)d_out;

    char* ws = (char*)d_ws;
    size_t off = 0;
    auto alloc = [&](size_t bytes) { void* p = ws + off; off += (bytes + 255) & ~(size_t)255; return p; };
    int*   deg       = (int*)  alloc(NN * 4);
    int*   ord       = (int*)  alloc((size_t)NE * 4);
    int*   row_start = (int*)  alloc(NN * 4);
    int*   bsum      = (int*)  alloc(128 * 4);
    float4* rec      = (float4*)alloc((size_t)NE2 * 16);
    unsigned short* h1b = (unsigned short*)alloc((size_t)NN * 64 * 2);
    float* as1       = (float*)alloc((size_t)NN * 4 * 4);
    float* ad1       = (float*)alloc((size_t)NN * 4 * 4);
    unsigned short* x1b = (unsigned short*)alloc((size_t)NN * 64 * 2);
    unsigned short* h2b = (unsigned short*)alloc((size_t)NN * 32 * 2);
    float* as2       = (float*)alloc(NN * 4);
    float* ad2       = (float*)alloc(NN * 4);
    (void)ws_size; (void)in_sizes; (void)n_in; (void)out_size;

    hipMemsetAsync(deg, 0, NN * 4, stream);

    k_node<<<(NN * 4 + 255) / 256, 256, 0, stream>>>(
        pol_feat, state_ids, sector_ids, industry_ids, comp_scalar,
        pol_W, pol_b, state_E, sector_E, industry_E, comp_W, comp_b, comm_E,
        ln_g, ln_b, c1_W, c1_as, c1_ad, h1b, as1, ad1);
    k_deg<<<(NE + 255) / 256, 256, 0, stream>>>(edge_index, deg, ord);
    int nblk = (NN + 1023) / 1024;   // 98
    k_scan1<<<nblk, 1024, 0, stream>>>(deg, row_start, bsum);
    k_scan2<<<1, 128, 0, stream>>>(bsum, nblk);
    k_scan3<<<(NN + 255) / 256, 256, 0, stream>>>(row_start, bsum);
    k_fill<<<(NE + 255) / 256, 256, 0, stream>>>(
        edge_index, edge_attr, row_start, ord, c1_eW, c1_ae, c2_eW, c2_ae, rec);
    k_agg1<<<NN / 8, 256, 0, stream>>>(
        row_start, deg, rec, as1, ad1, h1b, c1_b, x1b);
    k_mid<<<(NN / 2) / 4, 256, 0, stream>>>(          // 50000 waves = 12500 blocks
        x1b, c2_W, c2_as, c2_ad, h2b, as2, ad2);
    k_agg2<<<NN / 8, 256, 0, stream>>>(
        row_start, deg, rec, as2, ad2, h2b, c2_b, out);
}